// Round 23
// baseline (27.392 us; speedup 1.0000x reference)
//
#include <hip/hip_runtime.h>

// Problem constants
#define NSPLIT  100
#define MTREE   20
#define MAXLEAF 64
#define EMB     32
#define NTREES  2000
#define BATCH   4096
#define OUTW    (NSPLIT*EMB)            // 3200
#define SPLIT_B 81920                   // bf16 table bytes per split

#define THREADS 1024
#define NBLK    512                     // exactly 2 blocks/CU, zero imbalance
#define IPB     ((BATCH*NSPLIT)/NBLK)   // 800 (split,batch) pairs per block

// v23 = v22's fused-staging LDS-gather body + v5's balanced linearization.
// v22's 400-block grid: 144 CUs ran 2 blocks, 112 ran 1 -> wall carried
// 1.28x the balanced gather time. Here 512 blocks each own EXACTLY 800
// (split,batch) pairs -> every CU gets 1600 pairs of gather. ~1/5 of blocks
// cross a split boundary and re-stage mid-block (stagings 400 -> ~612,
// spread evenly), a fine trade for -22% on the critical path.
// v5's version of this shape failed for reasons since fixed: it gathered
// via the slow L1/global path (v11 measured its ~45us floor) and staged
// 16x-redundant f32; both replaced by the champion's LDS+fused-bf16 body.
__device__ __forceinline__ unsigned int pk_bf16(float a, float b) {
    unsigned int r;
    asm("v_cvt_pk_bf16_f32 %0, %1, %2" : "=v"(r) : "v"(a), "v"(b));
    return r;
}

// a += 1.0 * (selected bf16 half of w): one VOP3P dot2.
__device__ __forceinline__ void d2(float& a, unsigned int w, unsigned int sel) {
    asm("v_dot2_f32_bf16 %0, %1, %2, %0" : "+v"(a) : "v"(w), "v"(sel));
}

__global__ __launch_bounds__(THREADS, 1) void leaf2emb_v23(
    const int* __restrict__ leaves,     // [BATCH, NTREES]
    const float* __restrict__ embed,    // [NSPLIT, MTREE*MAXLEAF, EMB] f32
    float* __restrict__ out)            // [BATCH, OUTW]
{
    __shared__ char tl[SPLIT_B];        // 80 KiB: one split's table, bf16

    // XCD-chunked swizzle: 512 = 8 x 64 -> consecutive work ranges (and the
    // splits they stage) stay on one XCD's L2.
    const int bid = blockIdx.x;
    const int wkr = (bid & 7) * (NBLK / 8) + (bid >> 3);

    const int tid = threadIdx.x;
    const int l   = tid & 3;            // lane-in-group: dims [8l, 8l+8)
    const int g   = tid >> 2;           // group id (256 groups)

    int s      = (wkr * IPB) >> 12;     // current split
    int bstart = (wkr * IPB) & 4095;    // first batch of segment
    int remain = IPB;

    const unsigned int selL = 0x00003F80u;   // {hi=0, lo=1.0bf16}
    const unsigned int selH = 0x3F800000u;   // {hi=1.0bf16, lo=0}
    const char* tb  = tl + l * 16;
    const char* tbH = tb + 65536;       // trees 16..19 window (ds imm < 64K)

#define ROWL(T, LEAF) (*(const uint4*)(tb  + (T) * 4096 + ((LEAF) << 6)))
#define ROWH(T, LEAF) (*(const uint4*)(tbH + ((T) - 16) * 4096 + ((LEAF) << 6)))
#define D2ACC(V) { \
        d2(a0.x, (V).x, selL); d2(a0.y, (V).x, selH); \
        d2(a0.z, (V).y, selL); d2(a0.w, (V).y, selH); \
        d2(a1.x, (V).z, selL); d2(a1.y, (V).z, selH); \
        d2(a1.z, (V).w, selL); d2(a1.w, (V).w, selH); }

    while (remain > 0) {
        const int cnt = min(remain, BATCH - bstart);

        if (remain != IPB) __syncthreads();   // prev segment's gathers done

        // ---- fused staging: f32 global -> cvt_pk -> LINEAR bf16 LDS ----
        {
            const float4* emb4 = (const float4*)embed + (size_t)s * 10240;
#pragma unroll 2
            for (int k = 0; k < 10; ++k) {
                const int i = tid + k * 1024;
                const float4 v = emb4[i];
                *(uint2*)(tl + i * 8) =
                    make_uint2(pk_bf16(v.x, v.y), pk_bf16(v.z, v.w));
            }
        }
        __syncthreads();                      // table ready

        // ---- gather loop: group g handles batches bstart+g, +256, ... ----
        for (int b = bstart + g; b < bstart + cnt; b += 256) {
            const int4* lv = (const int4*)(leaves + (size_t)b * NTREES + s * MTREE);
            const int4 L0 = lv[0], L1 = lv[1], L2 = lv[2], L3 = lv[3], L4 = lv[4];

            float4 a0 = {0,0,0,0}, a1 = {0,0,0,0};
            uint4 v00 = ROWL(0,  L0.x), v01 = ROWL(1,  L0.y), v02 = ROWL(2,  L0.z), v03 = ROWL(3,  L0.w);
            uint4 v04 = ROWL(4,  L1.x), v05 = ROWL(5,  L1.y), v06 = ROWL(6,  L1.z), v07 = ROWL(7,  L1.w);
            uint4 v08 = ROWL(8,  L2.x), v09 = ROWL(9,  L2.y), v10 = ROWL(10, L2.z), v11 = ROWL(11, L2.w);
            uint4 v12 = ROWL(12, L3.x), v13 = ROWL(13, L3.y), v14 = ROWL(14, L3.z), v15 = ROWL(15, L3.w);
            uint4 v16 = ROWH(16, L4.x), v17 = ROWH(17, L4.y), v18 = ROWH(18, L4.z), v19 = ROWH(19, L4.w);
            D2ACC(v00) D2ACC(v01) D2ACC(v02) D2ACC(v03)
            D2ACC(v04) D2ACC(v05) D2ACC(v06) D2ACC(v07)
            D2ACC(v08) D2ACC(v09) D2ACC(v10) D2ACC(v11)
            D2ACC(v12) D2ACC(v13) D2ACC(v14) D2ACC(v15)
            D2ACC(v16) D2ACC(v17) D2ACC(v18) D2ACC(v19)

            float* o_ = out + (size_t)b * OUTW + s * EMB + l * 8;
            *(float4*)(o_)     = a0;
            *(float4*)(o_ + 4) = a1;
        }

        remain -= cnt;
        bstart = 0;
        s += 1;
    }

#undef ROWL
#undef ROWH
#undef D2ACC
}

extern "C" void kernel_launch(void* const* d_in, const int* in_sizes, int n_in,
                              void* d_out, int out_size, void* d_ws, size_t ws_size,
                              hipStream_t stream) {
    const int* leaves  = (const int*)d_in[0];
    const float* embed = (const float*)d_in[1];
    float* out         = (float*)d_out;

    leaf2emb_v23<<<dim3(NBLK), dim3(THREADS), 0, stream>>>(leaves, embed, out);
}

// Round 24
// 26.524 us; speedup vs baseline: 1.0327x; 1.0327x over previous
//
#include <hip/hip_runtime.h>

// Problem constants
#define NSPLIT  100
#define MTREE   20
#define MAXLEAF 64
#define EMB     32
#define NTREES  2000
#define BATCH   4096
#define OUTW    (NSPLIT*EMB)            // 3200
#define SPLIT_B 81920                   // bf16 table bytes per split

#define THREADS 1024
#define CHUNKS  4                       // batch-chunks per split
#define BPC     (BATCH/CHUNKS)          // 1024 batches/block, 4 per group
#define NBLK    (NSPLIT*CHUNKS)        // 400

// v24 = v22 restored (the 26.6us champion). Final structure; every piece is
// the measured winner of an explicit A/B over 23 rounds (78 -> 26.6us):
//  - whole split table as bf16 in 80 KiB static LDS (64B rows; one
//    ds_read_b128 covers a 4-lane group's full row);
//  - staging FUSED: f32 -> v_cvt_pk_bf16_f32 -> linear ds_write_b64
//    (separate cvt kernel: +4.3us; DMA from pre-cvt d_ws: +4us; padded
//    strides: conflicts UP; reg-depth games: neutral x3);
//  - v_dot2_f32_bf16 accumulate (shift/and/add: +3.7us);
//  - CHUNKS=4: 400 blocks, 4 sequential batches per 4-lane group with the
//    next batch's leaves loading under the current consume (CHUNKS=8: +3.3us;
//    balanced 512-block linearization: +0.8us -- re-staging/barrier costs
//    exceed the 1.28x imbalance saving);
//  - one barrier, 2 blocks/CU co-resident, XCD-chunked blockIdx swizzle.
// Residuals (measured): LDS port ~50% effective -- 16 random 64B rows per
// wave-instr intrinsically need >=8 bank-cycles regardless of layout (two
// re-stride attempts moved conflicts UP); HBM 21%; VALU 16%; the rest is
// gather latency the compiler refuses to pipeline deeper (VGPR allocator
// flattens to 2-3-deep; confirmed v15/v16/v21).
__device__ __forceinline__ unsigned int pk_bf16(float a, float b) {
    unsigned int r;
    asm("v_cvt_pk_bf16_f32 %0, %1, %2" : "=v"(r) : "v"(a), "v"(b));
    return r;
}

// a += 1.0 * (selected bf16 half of w): one VOP3P dot2.
__device__ __forceinline__ void d2(float& a, unsigned int w, unsigned int sel) {
    asm("v_dot2_f32_bf16 %0, %1, %2, %0" : "+v"(a) : "v"(w), "v"(sel));
}

__global__ __launch_bounds__(THREADS, 1) void leaf2emb_v24(
    const int* __restrict__ leaves,     // [BATCH, NTREES]
    const float* __restrict__ embed,    // [NSPLIT, MTREE*MAXLEAF, EMB] f32
    float* __restrict__ out)            // [BATCH, OUTW]
{
    __shared__ char tl[SPLIT_B];        // 80 KiB: whole split table, bf16

    // XCD-chunked swizzle: 400 = 8 x 50 -> a split's 4 blocks share an XCD;
    // its 1.6 MB f32 slice stays L2-resident across the 4 re-reads.
    const int bid = blockIdx.x;
    const int wkr = (bid & 7) * (NBLK / 8) + (bid >> 3);
    const int s     = wkr >> 2;
    const int chunk = wkr & 3;

    const int tid = threadIdx.x;
    const int l   = tid & 3;            // lane-in-group: dims [8l, 8l+8)
    const int g   = tid >> 2;           // group id (256 groups, 4 batches each)

    // ---- fused staging: f32 global -> cvt_pk -> LINEAR bf16 LDS ----
    {
        const float4* emb4 = (const float4*)embed + (size_t)s * 10240;
#pragma unroll 2
        for (int k = 0; k < 10; ++k) {
            const int i = tid + k * 1024;
            const float4 v = emb4[i];
            *(uint2*)(tl + i * 8) =
                make_uint2(pk_bf16(v.x, v.y), pk_bf16(v.z, v.w));
        }
    }

    const int b0 = chunk * BPC + g;     // batches b0, +256, +512, +768
    const int4* lv0 = (const int4*)(leaves + (size_t)b0 * NTREES + s * MTREE);
    const int4* lv1 = (const int4*)((const int*)lv0 + 256 * NTREES);
    const int4* lv2 = (const int4*)((const int*)lv0 + 512 * NTREES);
    const int4* lv3 = (const int4*)((const int*)lv0 + 768 * NTREES);

    // batch-0 leaves in flight during the staging tail
    int4 L0 = lv0[0], L1 = lv0[1], L2 = lv0[2], L3 = lv0[3], L4 = lv0[4];

    __syncthreads();                    // the kernel's ONLY barrier

    const char* tb  = tl + l * 16;
    const char* tbH = tb + 65536;       // trees 16..19 window (ds imm < 64K)

    const unsigned int selL = 0x00003F80u;   // {hi=0, lo=1.0bf16}
    const unsigned int selH = 0x3F800000u;   // {hi=1.0bf16, lo=0}

#define ROWL(T, LEAF) (*(const uint4*)(tb  + (T) * 4096 + ((LEAF) << 6)))
#define ROWH(T, LEAF) (*(const uint4*)(tbH + ((T) - 16) * 4096 + ((LEAF) << 6)))
#define D2ACC(V) { \
        d2(a0.x, (V).x, selL); d2(a0.y, (V).x, selH); \
        d2(a0.z, (V).y, selL); d2(a0.w, (V).y, selH); \
        d2(a1.x, (V).z, selL); d2(a1.y, (V).z, selH); \
        d2(a1.z, (V).w, selL); d2(a1.w, (V).w, selH); }

#define ISSUE(P0, P1, P2, P3, P4) \
    v00 = ROWL(0,(P0).x); v01 = ROWL(1,(P0).y); v02 = ROWL(2,(P0).z); v03 = ROWL(3,(P0).w); \
    v04 = ROWL(4,(P1).x); v05 = ROWL(5,(P1).y); v06 = ROWL(6,(P1).z); v07 = ROWL(7,(P1).w); \
    v08 = ROWL(8,(P2).x); v09 = ROWL(9,(P2).y); v10 = ROWL(10,(P2).z); v11 = ROWL(11,(P2).w); \
    v12 = ROWL(12,(P3).x); v13 = ROWL(13,(P3).y); v14 = ROWL(14,(P3).z); v15 = ROWL(15,(P3).w); \
    v16 = ROWH(16,(P4).x); v17 = ROWH(17,(P4).y); v18 = ROWH(18,(P4).z); v19 = ROWH(19,(P4).w);
#define CONSUME \
    D2ACC(v00) D2ACC(v01) D2ACC(v02) D2ACC(v03) \
    D2ACC(v04) D2ACC(v05) D2ACC(v06) D2ACC(v07) \
    D2ACC(v08) D2ACC(v09) D2ACC(v10) D2ACC(v11) \
    D2ACC(v12) D2ACC(v13) D2ACC(v14) D2ACC(v15) \
    D2ACC(v16) D2ACC(v17) D2ACC(v18) D2ACC(v19)
#define WRITEOUT(BB) { \
    float* o_ = out + (size_t)(BB) * OUTW + s * EMB + l * 8; \
    *(float4*)(o_)     = a0; \
    *(float4*)(o_ + 4) = a1; }

    uint4 v00, v01, v02, v03, v04, v05, v06, v07;
    uint4 v08, v09, v10, v11, v12, v13, v14, v15, v16, v17, v18, v19;
    float4 a0, a1;
    int4 M0, M1, M2, M3, M4;

    // ---- batch 0 (leaves L), batch-1 leaves load under consume ----
    a0 = make_float4(0,0,0,0); a1 = make_float4(0,0,0,0);
    ISSUE(L0, L1, L2, L3, L4)
    M0 = lv1[0]; M1 = lv1[1]; M2 = lv1[2]; M3 = lv1[3]; M4 = lv1[4];
    CONSUME
    WRITEOUT(b0)

    // ---- batch 1 (leaves M), batch-2 leaves load under consume ----
    a0 = make_float4(0,0,0,0); a1 = make_float4(0,0,0,0);
    ISSUE(M0, M1, M2, M3, M4)
    L0 = lv2[0]; L1 = lv2[1]; L2 = lv2[2]; L3 = lv2[3]; L4 = lv2[4];
    CONSUME
    WRITEOUT(b0 + 256)

    // ---- batch 2 (leaves L), batch-3 leaves load under consume ----
    a0 = make_float4(0,0,0,0); a1 = make_float4(0,0,0,0);
    ISSUE(L0, L1, L2, L3, L4)
    M0 = lv3[0]; M1 = lv3[1]; M2 = lv3[2]; M3 = lv3[3]; M4 = lv3[4];
    CONSUME
    WRITEOUT(b0 + 512)

    // ---- batch 3 (leaves M) ----
    a0 = make_float4(0,0,0,0); a1 = make_float4(0,0,0,0);
    ISSUE(M0, M1, M2, M3, M4)
    CONSUME
    WRITEOUT(b0 + 768)

#undef ROWL
#undef ROWH
#undef D2ACC
#undef ISSUE
#undef CONSUME
#undef WRITEOUT
}

extern "C" void kernel_launch(void* const* d_in, const int* in_sizes, int n_in,
                              void* d_out, int out_size, void* d_ws, size_t ws_size,
                              hipStream_t stream) {
    const int* leaves  = (const int*)d_in[0];
    const float* embed = (const float*)d_in[1];
    float* out         = (float*)d_out;

    leaf2emb_v24<<<dim3(NBLK), dim3(THREADS), 0, stream>>>(leaves, embed, out);
}